// Round 3
// baseline (187.941 us; speedup 1.0000x reference)
//
#include <hip/hip_runtime.h>

// DistributionLoss: local 7x7xC std (zero-padded) of two [16,3,512,512] fp32
// tensors, smooth-L1 mean between std maps -> scalar.
//
// R3: barrier-free register-resident design. Each thread computes a 4x4
// output patch. Per input row: 9 aligned float4 loads (3 planes x 3 groups,
// neighbor overlap served by L1), channel reduce, sliding 7-tap horizontal,
// direct accumulation into <=7 overlapping row accumulators (statically
// unrolled). Input 0's std quads stay in registers; input 1 fuses smooth-L1.
// No LDS staging, no barriers -> pure latency hiding via 16 waves/CU + ILP.

#define K   7
#define PAD 3
#define NY  4
#define NT  256

__global__ __launch_bounds__(NT, 4) void dist_loss_kernel(
    const float* __restrict__ pred,
    const float* __restrict__ tgt,
    float* __restrict__ out)
{
    constexpr int   C = 3, H = 512, W = 512;
    constexpr float INV_N     = 1.0f / (C * K * K);              // 1/147
    constexpr float INV_TOTAL = 1.0f / (16.0f * 512.0f * 512.0f);

    const int tid = threadIdx.x;
    const int xg  = tid & 127;          // float4 column group 0..127
    const int x0  = xg << 2;            // first output column
    const int strip = (blockIdx.x << 1) + (tid >> 7);   // wave-uniform
    const int y0  = strip * NY;         // first output row
    const int b   = blockIdx.y;
    const size_t plane = (size_t)H * W;

    const bool leftOK  = (xg > 0);
    const bool rightOK = (xg < 127);
    const float4 z4 = make_float4(0.f, 0.f, 0.f, 0.f);

    float4 sdPrev[NY];
    float  acc = 0.0f;

    #pragma unroll
    for (int which = 0; which < 2; ++which) {
        const float* base = (which == 0 ? pred : tgt) + (size_t)b * C * plane;

        float4 accS[NY], accS2[NY];
        #pragma unroll
        for (int j = 0; j < NY; ++j) { accS[j] = z4; accS2[j] = z4; }

        #pragma unroll
        for (int i = 0; i < NY + 2 * PAD; ++i) {
            const int gy = y0 - PAD + i;
            if ((unsigned)gy < (unsigned)H) {      // wave-uniform predicate
                float t[12], t2[12];
                #pragma unroll
                for (int q = 0; q < 12; ++q) { t[q] = 0.f; t2[q] = 0.f; }

                #pragma unroll
                for (int c = 0; c < C; ++c) {
                    const float* rp = base + (size_t)c * plane + (size_t)gy * W + x0;
                    float4 va = leftOK  ? *(const float4*)(rp - 4) : z4;
                    float4 vb = *(const float4*)(rp);
                    float4 vc = rightOK ? *(const float4*)(rp + 4) : z4;
                    float v[12] = { va.x, va.y, va.z, va.w,
                                    vb.x, vb.y, vb.z, vb.w,
                                    vc.x, vc.y, vc.z, vc.w };
                    #pragma unroll
                    for (int q = 0; q < 12; ++q) {
                        t [q] += v[q];
                        t2[q]  = fmaf(v[q], v[q], t2[q]);
                    }
                }

                // sliding 7-tap horizontal: outputs x0..x0+3
                float h0 = t[1] + t[2] + t[3] + t[4] + t[5] + t[6] + t[7];
                float h1 = h0 - t[1] + t[8];
                float h2 = h1 - t[2] + t[9];
                float h3 = h2 - t[3] + t[10];
                float g0 = t2[1] + t2[2] + t2[3] + t2[4] + t2[5] + t2[6] + t2[7];
                float g1 = g0 - t2[1] + t2[8];
                float g2 = g1 - t2[2] + t2[9];
                float g3 = g2 - t2[3] + t2[10];

                // accumulate into overlapping output rows (static bounds)
                #pragma unroll
                for (int j = 0; j < NY; ++j) {
                    if (j >= i - (K - 1) && j <= i) {
                        accS [j].x += h0; accS [j].y += h1;
                        accS [j].z += h2; accS [j].w += h3;
                        accS2[j].x += g0; accS2[j].y += g1;
                        accS2[j].z += g2; accS2[j].w += g3;
                    }
                }
            }
        }

        // epilogue: std per pixel; input 0 parks, input 1 fuses smooth-L1
        #pragma unroll
        for (int j = 0; j < NY; ++j) {
            float4 sd;
            #pragma unroll
            for (int q = 0; q < 4; ++q) {
                float sv  = (&accS [j].x)[q];
                float sv2 = (&accS2[j].x)[q];
                float mu  = sv * INV_N;
                float var = fmaf(-mu, mu, sv2 * INV_N);
                (&sd.x)[q] = sqrtf(var + 1e-8f);
            }
            if (which == 0) {
                sdPrev[j] = sd;
            } else {
                #pragma unroll
                for (int q = 0; q < 4; ++q) {
                    float d  = (&sdPrev[j].x)[q] - (&sd.x)[q];
                    float ad = fabsf(d);
                    acc += (ad < 1.0f) ? 0.5f * d * d : (ad - 0.5f);
                }
            }
        }
    }

    // block reduction: wave64 shuffle, cross-wave via LDS, one atomic
    #pragma unroll
    for (int off = 32; off > 0; off >>= 1)
        acc += __shfl_down(acc, off, 64);

    __shared__ float wave_sums[NT / 64];
    if ((tid & 63) == 0) wave_sums[tid >> 6] = acc;
    __syncthreads();
    if (tid == 0) {
        float s = 0.0f;
        #pragma unroll
        for (int w = 0; w < NT / 64; ++w) s += wave_sums[w];
        atomicAdd(out, s * INV_TOTAL);
    }
}

extern "C" void kernel_launch(void* const* d_in, const int* in_sizes, int n_in,
                              void* d_out, int out_size, void* d_ws, size_t ws_size,
                              hipStream_t stream) {
    const float* pred = (const float*)d_in[0];
    const float* tgt  = (const float*)d_in[1];
    float* out = (float*)d_out;

    hipMemsetAsync(out, 0, sizeof(float), stream);

    // 64 strip-pairs (512 rows / NY=4 / 2 strips per block) x 16 batches
    dim3 grid(64, 16);
    dist_loss_kernel<<<grid, NT, 0, stream>>>(pred, tgt, out);
}